// Round 4
// baseline (7653.419 us; speedup 1.0000x reference)
//
#include <hip/hip_runtime.h>
#include <math.h>

#define NTHR 512

// ---------------------------------------------------------------- uncached ops
__device__ __forceinline__ void st_uc(float* p, float v) {
    asm volatile("global_store_dword %0, %1, off sc0 sc1" :: "v"(p), "v"(v) : "memory");
}
__device__ __forceinline__ void st_uc_u(unsigned* p, unsigned v) {
    asm volatile("global_store_dword %0, %1, off sc0 sc1" :: "v"(p), "v"(v) : "memory");
}
__device__ __forceinline__ float4 ld_uc4(const float4* p) {
    float4 v;
    asm volatile("global_load_dwordx4 %0, %1, off sc0 sc1" : "=v"(v) : "v"(p) : "memory");
    return v;
}
// spin until *p >= target (uncached so we see remote publishes)
__device__ __forceinline__ void spin_tag(const unsigned* p, unsigned target) {
    unsigned v;
    do {
        asm volatile("global_load_dword %0, %1, off sc0 sc1\n\ts_waitcnt vmcnt(0)"
                     : "=v"(v) : "v"(p) : "memory");
    } while (v < target);
}

// ---------------------------------------------------------------- init
// h_buf: 2 slots x 32768 floats; g_buf same; tags: 4 groups x 128 uints.
__global__ void init_kernel(float* h_buf, unsigned* tags) {
    int i = blockIdx.x * blockDim.x + threadIdx.x;
    if (i < 65536) st_uc(h_buf + i, 0.0f);
    if (i < 512) st_uc_u(tags + i, 0u);
}

// ---------------------------------------------------------------- xb = x @ b
__global__ __launch_bounds__(256) void xb_gemm(const float* __restrict__ X,
                                               const float* __restrict__ Bw,
                                               float* __restrict__ XB) {
    __shared__ float xs[16][132];
    __shared__ float bs[16][132];
    const int bm = blockIdx.x >> 3;
    const int bn = blockIdx.x & 7;
    const int m0 = bm * 128, n0 = bn * 128;
    const int tid = threadIdx.x;
    const int tx = tid & 15, ty = tid >> 4;
    float acc[8][8];
#pragma unroll
    for (int i = 0; i < 8; ++i)
#pragma unroll
        for (int j = 0; j < 8; ++j) acc[i][j] = 0.f;

    for (int k0 = 0; k0 < 1024; k0 += 16) {
#pragma unroll
        for (int p = 0; p < 2; ++p) {
            int f = tid + p * 256;
            int m = f >> 2, kq = f & 3;
            float4 v = *(const float4*)&X[(size_t)(m0 + m) * 1024 + k0 + kq * 4];
            xs[kq * 4 + 0][m] = v.x; xs[kq * 4 + 1][m] = v.y;
            xs[kq * 4 + 2][m] = v.z; xs[kq * 4 + 3][m] = v.w;
        }
#pragma unroll
        for (int p = 0; p < 2; ++p) {
            int f = tid + p * 256;
            int k = f >> 5, n = (f & 31) * 4;
            float4 v = *(const float4*)&Bw[(size_t)(k0 + k) * 1024 + n0 + n];
            *(float4*)&bs[k][n] = v;
        }
        __syncthreads();
#pragma unroll
        for (int k = 0; k < 16; ++k) {
            float xv[8], bv[8];
            *(float4*)&xv[0] = *(const float4*)&xs[k][ty * 8];
            *(float4*)&xv[4] = *(const float4*)&xs[k][ty * 8 + 4];
            *(float4*)&bv[0] = *(const float4*)&bs[k][tx * 8];
            *(float4*)&bv[4] = *(const float4*)&bs[k][tx * 8 + 4];
#pragma unroll
            for (int i = 0; i < 8; ++i)
#pragma unroll
                for (int j = 0; j < 8; ++j) acc[i][j] += xv[i] * bv[j];
        }
        __syncthreads();
    }
#pragma unroll
    for (int i = 0; i < 8; ++i)
#pragma unroll
        for (int j = 0; j < 8; j += 4) {
            float4 v = make_float4(acc[i][j], acc[i][j + 1], acc[i][j + 2], acc[i][j + 3]);
            *(float4*)&XB[(size_t)(m0 + ty * 8 + i) * 1024 + n0 + tx * 8 + j] = v;
        }
}

// ---------------------------------------------------------------- persistent scan
// 256 WGs = 4 batch-groups (8 batches) x 64 col-slices (16 cols).
// Exchange protocol: per-slice monotonic tags (tag=t+1 after data of step t is
// drained to LLC with uncached stores), 2-slot ping-pong h/g buffers (slot=t&1
// for writes at step t; reads of h(t-1) from slot (t+1)&1). No atomics, no
// grid barrier. Wave 0 owns all 128 epilogue outputs + cell state, publishes
// after a wave-local vmcnt(0); waves 1-7 spin+issue staging loads meanwhile.
__global__ __launch_bounds__(NTHR, 1) void scan_kernel(
    const float* __restrict__ A, const float* __restrict__ CTm,
    float* __restrict__ XBH, float* __restrict__ h_buf, float* __restrict__ g_buf,
    float* __restrict__ ht_out, float* __restrict__ ct_out, unsigned* __restrict__ tags) {
    extern __shared__ float lds[];
    float* a_lf  = lds;                   // [16 cols][1024] col-major
    float* ct_lf = lds + 16384;
    float* hg_f  = lds + 32768;           // staging 8192 floats; scr aliases head
    float4* a_l4  = (float4*)a_lf;
    float4* ct_l4 = (float4*)ct_lf;
    float4* hg_4  = (float4*)hg_f;
    float* scr = hg_f;                    // 512 floats

    const int wg = blockIdx.x;
    const int bg = wg >> 6;
    const int sg = wg & 63;
    const int c0wg = sg * 16;
    const int tid = threadIdx.x;
    unsigned* tagH = tags + (bg << 7);
    unsigned* tagG = tagH + 64;

    // ---- one-time weight preload: columns c0wg..c0wg+15, linear col-major ----
    {
        const int c = tid & 15, i0 = tid >> 4;
        for (int i = i0; i < 1024; i += 32) {
            a_lf[c * 1024 + i]  = A[(size_t)i * 1024 + c0wg + c];
            ct_lf[c * 1024 + i] = CTm[(size_t)i * 1024 + c0wg + c];
        }
    }

    const int L  = tid & 63;
    const int w  = tid >> 6;
    const int Lc = L & 7;
    const int Lb = (L >> 3) & 7;
    const int cgA = w & 1, kqA = w >> 1;
    const int gB  = w >> 1;

    int hIdx[8], aIdx[8], gIdx[8], cIdx[8];
#pragma unroll
    for (int r = 0; r < 8; ++r) hIdx[r] = (r ^ Lb) * 256 + kqA * 64 + L;
#pragma unroll
    for (int c = 0; c < 8; ++c) aIdx[c] = (cgA * 8 + (c ^ Lc)) * 256 + kqA * 64 + L;
#pragma unroll
    for (int r = 0; r < 8; ++r) gIdx[r] = (r ^ Lb) * 256 + gB * 64 + L;
#pragma unroll
    for (int c = 0; c < 8; ++c) cIdx[c] = (cgA * 8 + (c ^ Lc)) * 256 + gB * 64 + L;

    // which slice's tag this thread's staging loads depend on
    const int jneed = (tid >> 2) & 63;

    // wave-0 epilogue mapping: lane L handles pairs p0=L (b=L>>4), p1=L+64 (b=4+L>>4)
    const int e_b0 = L >> 4;
    const int e_j  = L & 15;
    const int e_cg = e_j >> 3;
    const int e_s0 = e_b0 * 8 + (e_j & 7);
    const int e_s1 = (e_b0 + 4) * 8 + (e_j & 7);
    const int bglob0 = bg * 8 + e_b0;
    const int bglob1 = bglob0 + 4;
    const int e_col  = c0wg + e_j;

    float4* h4 = (float4*)h_buf;
    float4* g4 = (float4*)g_buf;

    float creg0 = 0.f, creg1 = 0.f;
    __syncthreads();   // weights ready

    for (int t = 0; t < 512; ++t) {
        const unsigned tu = (unsigned)t;
        // ================= phase A =================
        // wait for h(t-1) of my needed slice, then stage (slot (t+1)&1)
        spin_tag(tagH + jneed, tu);
        {
            const float4* hb = h4 + ((t + 1) & 1) * 8192 + bg * 2048;
            float4 v0 = ld_uc4(hb + tid);
            float4 v1 = ld_uc4(hb + 512 + tid);
            float4 v2 = ld_uc4(hb + 1024 + tid);
            float4 v3 = ld_uc4(hb + 1536 + tid);
            asm volatile("s_waitcnt vmcnt(0)" ::: "memory");
            __builtin_amdgcn_sched_barrier(0);
            hg_4[tid] = v0; hg_4[512 + tid] = v1; hg_4[1024 + tid] = v2; hg_4[1536 + tid] = v3;
            __syncthreads();
        }
        // xb prefetch (wave 0, cached; line exclusive to this WG this step)
        float xb0 = 0.f, xb1 = 0.f;
        if (w == 0) {
            xb0 = XBH[((size_t)bglob0 * 512 + t) * 1024 + e_col];
            xb1 = XBH[((size_t)bglob1 * 512 + t) * 1024 + e_col];
        }
        // dots + butterfly
        float v[64];
        {
            float4 hv[8], av[8];
#pragma unroll
            for (int r = 0; r < 8; ++r) hv[r] = hg_4[hIdx[r]];
#pragma unroll
            for (int c = 0; c < 8; ++c) av[c] = a_l4[aIdx[c]];
#pragma unroll
            for (int r = 0; r < 8; ++r)
#pragma unroll
                for (int c = 0; c < 8; ++c)
                    v[r * 8 + c] = hv[r].x * av[c].x + hv[r].y * av[c].y
                                 + hv[r].z * av[c].z + hv[r].w * av[c].w;
        }
#pragma unroll
        for (int j = 0; j < 32; ++j) v[j] = v[2 * j] + __shfl_xor(v[2 * j + 1], 1);
#pragma unroll
        for (int j = 0; j < 16; ++j) v[j] = v[2 * j] + __shfl_xor(v[2 * j + 1], 2);
#pragma unroll
        for (int j = 0; j < 8; ++j)  v[j] = v[2 * j] + __shfl_xor(v[2 * j + 1], 4);
#pragma unroll
        for (int j = 0; j < 4; ++j)  v[j] = v[2 * j] + __shfl_xor(v[2 * j + 1], 8);
#pragma unroll
        for (int j = 0; j < 2; ++j)  v[j] = v[2 * j] + __shfl_xor(v[2 * j + 1], 16);
        v[0] = v[0] + __shfl_xor(v[1], 32);

        __syncthreads();                  // all hg reads done (scr aliases hg)
        scr[w * 64 + L] = v[0];
        __syncthreads();
        float sA0 = 0.f, sA1 = 0.f;
        if (w == 0) {
#pragma unroll
            for (int kq = 0; kq < 4; ++kq) {
                sA0 += scr[(kq * 2 + e_cg) * 64 + e_s0];
                sA1 += scr[(kq * 2 + e_cg) * 64 + e_s1];
            }
        }
        __syncthreads();                  // scr values safely in wave-0 regs
        if (w == 0) {
            float* gw = g_buf + (t & 1) * 32768;
            st_uc(gw + (size_t)bglob0 * 1024 + e_col, sA0 * xb0);
            st_uc(gw + (size_t)bglob1 * 1024 + e_col, sA1 * xb1);
            asm volatile("s_waitcnt vmcnt(0)" ::: "memory");
            if (L == 0) st_uc_u(tagG + sg, tu + 1u);
        }

        // ================= phase B =================
        spin_tag(tagG + jneed, tu + 1u);
        {
            const float4* gb = g4 + (t & 1) * 8192 + bg * 2048;
            float4 v0 = ld_uc4(gb + tid);
            float4 v1 = ld_uc4(gb + 512 + tid);
            float4 v2 = ld_uc4(gb + 1024 + tid);
            float4 v3 = ld_uc4(gb + 1536 + tid);
            asm volatile("s_waitcnt vmcnt(0)" ::: "memory");
            __builtin_amdgcn_sched_barrier(0);
            hg_4[tid] = v0; hg_4[512 + tid] = v1; hg_4[1024 + tid] = v2; hg_4[1536 + tid] = v3;
            __syncthreads();
        }
        {
            float4 gv[8], cv[8];
#pragma unroll
            for (int r = 0; r < 8; ++r) gv[r] = hg_4[gIdx[r]];
#pragma unroll
            for (int c = 0; c < 8; ++c) cv[c] = ct_l4[cIdx[c]];
#pragma unroll
            for (int r = 0; r < 8; ++r)
#pragma unroll
                for (int c = 0; c < 8; ++c)
                    v[r * 8 + c] = gv[r].x * cv[c].x + gv[r].y * cv[c].y
                                 + gv[r].z * cv[c].z + gv[r].w * cv[c].w;
        }
#pragma unroll
        for (int j = 0; j < 32; ++j) v[j] = v[2 * j] + __shfl_xor(v[2 * j + 1], 1);
#pragma unroll
        for (int j = 0; j < 16; ++j) v[j] = v[2 * j] + __shfl_xor(v[2 * j + 1], 2);
#pragma unroll
        for (int j = 0; j < 8; ++j)  v[j] = v[2 * j] + __shfl_xor(v[2 * j + 1], 4);
#pragma unroll
        for (int j = 0; j < 4; ++j)  v[j] = v[2 * j] + __shfl_xor(v[2 * j + 1], 8);
#pragma unroll
        for (int j = 0; j < 2; ++j)  v[j] = v[2 * j] + __shfl_xor(v[2 * j + 1], 16);
        v[0] = v[0] + __shfl_xor(v[1], 32);

        __syncthreads();
        scr[w * 64 + L] = v[0];
        __syncthreads();
        float pf0 = 0.f, pi0 = 0.f, pg0 = 0.f, po0 = 0.f;
        float pf1 = 0.f, pi1 = 0.f, pg1 = 0.f, po1 = 0.f;
        if (w == 0) {
            pf0 = scr[(0 + e_cg) * 64 + e_s0]; pi0 = scr[(2 + e_cg) * 64 + e_s0];
            pg0 = scr[(4 + e_cg) * 64 + e_s0]; po0 = scr[(6 + e_cg) * 64 + e_s0];
            pf1 = scr[(0 + e_cg) * 64 + e_s1]; pi1 = scr[(2 + e_cg) * 64 + e_s1];
            pg1 = scr[(4 + e_cg) * 64 + e_s1]; po1 = scr[(6 + e_cg) * 64 + e_s1];
        }
        __syncthreads();
        if (w == 0) {
            float ft = 1.f / (1.f + __expf(-pf0));
            float it = 1.f / (1.f + __expf(-pi0));
            float gt = tanhf(pg0);
            float ot = 1.f / (1.f + __expf(-po0));
            creg0 = ft * creg0 + it * gt;
            float hv0 = ot * tanhf(creg0);
            ft = 1.f / (1.f + __expf(-pf1));
            it = 1.f / (1.f + __expf(-pi1));
            gt = tanhf(pg1);
            ot = 1.f / (1.f + __expf(-po1));
            creg1 = ft * creg1 + it * gt;
            float hv1 = ot * tanhf(creg1);
            float* hw = h_buf + (t & 1) * 32768;
            st_uc(hw + (size_t)bglob0 * 1024 + e_col, hv0);
            st_uc(hw + (size_t)bglob1 * 1024 + e_col, hv1);
            st_uc(XBH + ((size_t)bglob0 * 512 + t) * 1024 + e_col, hv0);
            st_uc(XBH + ((size_t)bglob1 * 512 + t) * 1024 + e_col, hv1);
            if (t == 511) {
                st_uc(ht_out + (size_t)bglob0 * 1024 + e_col, hv0);
                st_uc(ht_out + (size_t)bglob1 * 1024 + e_col, hv1);
                st_uc(ct_out + (size_t)bglob0 * 1024 + e_col, creg0);
                st_uc(ct_out + (size_t)bglob1 * 1024 + e_col, creg1);
            }
            asm volatile("s_waitcnt vmcnt(0)" ::: "memory");
            if (L == 0) st_uc_u(tagH + sg, tu + 1u);
        }
    }
}

// ---------------------------------------------------------------- launch
extern "C" void kernel_launch(void* const* d_in, const int* in_sizes, int n_in,
                              void* d_out, int out_size, void* d_ws, size_t ws_size,
                              hipStream_t stream) {
    const float* X   = (const float*)d_in[0];
    const float* A   = (const float*)d_in[1];
    const float* Bw  = (const float*)d_in[2];
    const float* CTm = (const float*)d_in[3];

    float* out    = (float*)d_out;
    float* XBH    = out;                                  // xb in, hidden_seq out
    float* ht_out = out + (size_t)32 * 512 * 1024;
    float* ct_out = ht_out + 32 * 1024;

    float* h_buf = (float*)d_ws;                          // 2 x 32768 floats
    float* g_buf = h_buf + 65536;                         // 2 x 32768 floats
    unsigned* tags = (unsigned*)(g_buf + 65536);          // 4 x 128 uints

    (void)hipFuncSetAttribute((const void*)scan_kernel,
                              hipFuncAttributeMaxDynamicSharedMemorySize, 163840);

    init_kernel<<<dim3(256), dim3(256), 0, stream>>>(h_buf, tags);
    xb_gemm<<<dim3(1024), dim3(256), 0, stream>>>(X, Bw, XBH);
    scan_kernel<<<dim3(256), dim3(NTHR), 163840, stream>>>(A, CTm, XBH, h_buf, g_buf,
                                                           ht_out, ct_out, tags);
}

// Round 5
// 6930.824 us; speedup vs baseline: 1.1043x; 1.1043x over previous
//
#include <hip/hip_runtime.h>
#include <math.h>

#define NTHR 512

// ---------------------------------------------------------------- uncached ops
__device__ __forceinline__ void st_uc(float* p, float v) {
    asm volatile("global_store_dword %0, %1, off sc0 sc1" :: "v"(p), "v"(v) : "memory");
}
__device__ __forceinline__ void st_uc_u(unsigned* p, unsigned v) {
    asm volatile("global_store_dword %0, %1, off sc0 sc1" :: "v"(p), "v"(v) : "memory");
}
__device__ __forceinline__ float4 ld_uc4_nw(const float4* p) {   // no wait; caller drains vmcnt
    float4 v;
    asm volatile("global_load_dwordx4 %0, %1, off sc0 sc1" : "=v"(v) : "v"(p) : "memory");
    return v;
}
// all 64 lanes poll qbase[L&15] (one 64B line = this wave's 16 slice tags)
__device__ __forceinline__ void spin_tags(const unsigned* qbase, int lane15, unsigned target) {
    const unsigned* p = qbase + lane15;
    for (;;) {
        unsigned v;
        asm volatile("global_load_dword %0, %1, off sc0 sc1\n\ts_waitcnt vmcnt(0)"
                     : "=v"(v) : "v"(p) : "memory");
        if (!__any((int)(v < target))) return;
        __builtin_amdgcn_s_sleep(2);
    }
}

// ---------------------------------------------------------------- init
// h_buf: 2 slots x 32768 floats (both zeroed = h(-1)); tags: 4 bg x 128 uints.
__global__ void init_kernel(float* h_buf, unsigned* tags) {
    int i = blockIdx.x * blockDim.x + threadIdx.x;
    if (i < 65536) st_uc(h_buf + i, 0.0f);
    if (i < 512) st_uc_u(tags + i, 0u);
}

// ---------------------------------------------------------------- xb = x @ b
__global__ __launch_bounds__(256) void xb_gemm(const float* __restrict__ X,
                                               const float* __restrict__ Bw,
                                               float* __restrict__ XB) {
    __shared__ float xs[16][132];
    __shared__ float bs[16][132];
    const int bm = blockIdx.x >> 3;
    const int bn = blockIdx.x & 7;
    const int m0 = bm * 128, n0 = bn * 128;
    const int tid = threadIdx.x;
    const int tx = tid & 15, ty = tid >> 4;
    float acc[8][8];
#pragma unroll
    for (int i = 0; i < 8; ++i)
#pragma unroll
        for (int j = 0; j < 8; ++j) acc[i][j] = 0.f;

    for (int k0 = 0; k0 < 1024; k0 += 16) {
#pragma unroll
        for (int p = 0; p < 2; ++p) {
            int f = tid + p * 256;
            int m = f >> 2, kq = f & 3;
            float4 v = *(const float4*)&X[(size_t)(m0 + m) * 1024 + k0 + kq * 4];
            xs[kq * 4 + 0][m] = v.x; xs[kq * 4 + 1][m] = v.y;
            xs[kq * 4 + 2][m] = v.z; xs[kq * 4 + 3][m] = v.w;
        }
#pragma unroll
        for (int p = 0; p < 2; ++p) {
            int f = tid + p * 256;
            int k = f >> 5, n = (f & 31) * 4;
            float4 v = *(const float4*)&Bw[(size_t)(k0 + k) * 1024 + n0 + n];
            *(float4*)&bs[k][n] = v;
        }
        __syncthreads();
#pragma unroll
        for (int k = 0; k < 16; ++k) {
            float xv[8], bv[8];
            *(float4*)&xv[0] = *(const float4*)&xs[k][ty * 8];
            *(float4*)&xv[4] = *(const float4*)&xs[k][ty * 8 + 4];
            *(float4*)&bv[0] = *(const float4*)&bs[k][tx * 8];
            *(float4*)&bv[4] = *(const float4*)&bs[k][tx * 8 + 4];
#pragma unroll
            for (int i = 0; i < 8; ++i)
#pragma unroll
                for (int j = 0; j < 8; ++j) acc[i][j] += xv[i] * bv[j];
        }
        __syncthreads();
    }
#pragma unroll
    for (int i = 0; i < 8; ++i)
#pragma unroll
        for (int j = 0; j < 8; j += 4) {
            float4 v = make_float4(acc[i][j], acc[i][j + 1], acc[i][j + 2], acc[i][j + 3]);
            *(float4*)&XB[(size_t)(m0 + ty * 8 + i) * 1024 + n0 + tx * 8 + j] = v;
        }
}

// ---------------------------------------------------------------- persistent scan
// 256 WGs = 4 batch-groups (8 batches) x 64 col-slices (16 cols).
// Per-slice monotonic tags + depth-2 ping-pong h/g (protocol proven r4).
// New this round: wave-granular 1-line tag polling, direct-from-LLC h/g reads
// (no LDS staging), epilogue-A on wave0 / epilogue-B + cell state on wave4.
// 2 syncthreads per step (scrA/scrB separate; cross-step reuse gated by tags).
__global__ __launch_bounds__(NTHR, 1) void scan_kernel(
    const float* __restrict__ A, const float* __restrict__ CTm,
    float* __restrict__ XBH, float* __restrict__ h_buf, float* __restrict__ g_buf,
    float* __restrict__ ht_out, float* __restrict__ ct_out, unsigned* __restrict__ tags) {
    extern __shared__ float lds[];
    float* a_lf  = lds;                   // [16 cols][1024] col-major
    float* ct_lf = lds + 16384;
    float* scrA  = lds + 32768;           // 512 floats
    float* scrB  = lds + 33280;           // 512 floats
    float4* a_l4  = (float4*)a_lf;
    float4* ct_l4 = (float4*)ct_lf;

    const int wg = blockIdx.x;
    const int bg = wg >> 6;
    const int sg = wg & 63;
    const int c0wg = sg * 16;
    const int tid = threadIdx.x;
    unsigned* tagH = tags + (bg << 7);
    unsigned* tagG = tagH + 64;

    // ---- one-time weight preload: columns c0wg..c0wg+15, linear col-major ----
    {
        const int c = tid & 15, i0 = tid >> 4;
        for (int i = i0; i < 1024; i += 32) {
            a_lf[c * 1024 + i]  = A[(size_t)i * 1024 + c0wg + c];
            ct_lf[c * 1024 + i] = CTm[(size_t)i * 1024 + c0wg + c];
        }
    }

    const int L  = tid & 63;
    const int w  = tid >> 6;
    const int Lc = L & 7;
    const int Lb = (L >> 3) & 7;
    const int cg = w & 1, kq = w >> 1;

    int aIdx[8], xOff[8];
#pragma unroll
    for (int c = 0; c < 8; ++c) aIdx[c] = (cg * 8 + (c ^ Lc)) * 256 + kq * 64 + L;
#pragma unroll
    for (int r = 0; r < 8; ++r) xOff[r] = (r ^ Lb) * 256 + kq * 64 + L;

    const unsigned* myTagH = tagH + kq * 16;   // wave's quarter (one 64B line)
    const unsigned* myTagG = tagG + kq * 16;
    const int l15 = L & 15;

    // epilogue lane mapping (used by wave0 for A, wave4 for B): 2 outputs/lane
    const int e_b0 = L >> 4;
    const int e_j  = L & 15;
    const int e_cg = e_j >> 3;
    const int e_s0 = e_b0 * 8 + (e_j & 7);
    const int e_s1 = e_s0 + 32;
    const int bglob0 = bg * 8 + e_b0;
    const int bglob1 = bglob0 + 4;
    const int e_col  = c0wg + e_j;

    float4* h4 = (float4*)h_buf;
    float4* g4 = (float4*)g_buf;

    float creg0 = 0.f, creg1 = 0.f;       // live in wave4
    __syncthreads();   // weights ready

    for (int t = 0; t < 512; ++t) {
        const unsigned tu = (unsigned)t;
        // ---------------- phase A ----------------
        float xb0 = 0.f, xb1 = 0.f;
        if (w == 0) {   // xb prefetch (cached; resident in L3)
            xb0 = XBH[((size_t)bglob0 * 512 + t) * 1024 + e_col];
            xb1 = XBH[((size_t)bglob1 * 512 + t) * 1024 + e_col];
        }
        float4 av[8];
#pragma unroll
        for (int c = 0; c < 8; ++c) av[c] = a_l4[aIdx[c]];

        spin_tags(myTagH, l15, tu);
        const float4* hb = h4 + ((t + 1) & 1) * 8192 + bg * 2048;
        float4 hv[8];
#pragma unroll
        for (int r = 0; r < 8; ++r) hv[r] = ld_uc4_nw(hb + xOff[r]);
        asm volatile("s_waitcnt vmcnt(0)" ::: "memory");
        __builtin_amdgcn_sched_barrier(0);

        float v[64];
#pragma unroll
        for (int r = 0; r < 8; ++r)
#pragma unroll
            for (int c = 0; c < 8; ++c)
                v[r * 8 + c] = hv[r].x * av[c].x + hv[r].y * av[c].y
                             + hv[r].z * av[c].z + hv[r].w * av[c].w;
#pragma unroll
        for (int j = 0; j < 32; ++j) v[j] = v[2 * j] + __shfl_xor(v[2 * j + 1], 1);
#pragma unroll
        for (int j = 0; j < 16; ++j) v[j] = v[2 * j] + __shfl_xor(v[2 * j + 1], 2);
#pragma unroll
        for (int j = 0; j < 8; ++j)  v[j] = v[2 * j] + __shfl_xor(v[2 * j + 1], 4);
#pragma unroll
        for (int j = 0; j < 4; ++j)  v[j] = v[2 * j] + __shfl_xor(v[2 * j + 1], 8);
#pragma unroll
        for (int j = 0; j < 2; ++j)  v[j] = v[2 * j] + __shfl_xor(v[2 * j + 1], 16);
        v[0] = v[0] + __shfl_xor(v[1], 32);
        scrA[w * 64 + L] = v[0];
        __syncthreads();                  // sync1

        if (w == 0) {                     // epilogue A: g = (h@A)*xb, publish tagG
            float sA0 = 0.f, sA1 = 0.f;
#pragma unroll
            for (int k2 = 0; k2 < 4; ++k2) {
                sA0 += scrA[(k2 * 2 + e_cg) * 64 + e_s0];
                sA1 += scrA[(k2 * 2 + e_cg) * 64 + e_s1];
            }
            float* gw = g_buf + (t & 1) * 32768;
            st_uc(gw + (size_t)bglob0 * 1024 + e_col, sA0 * xb0);
            st_uc(gw + (size_t)bglob1 * 1024 + e_col, sA1 * xb1);
            asm volatile("s_waitcnt vmcnt(0)" ::: "memory");
            if (L == 0) st_uc_u(tagG + sg, tu + 1u);
        }

        // ---------------- phase B ----------------
        float4 cv[8];
#pragma unroll
        for (int c = 0; c < 8; ++c) cv[c] = ct_l4[aIdx[c] + 16384 / 4 - 16384 / 4];  // same idx
#pragma unroll
        for (int c = 0; c < 8; ++c) cv[c] = ct_l4[aIdx[c]];

        spin_tags(myTagG, l15, tu + 1u);
        const float4* gb = g4 + (t & 1) * 8192 + bg * 2048;
        float4 gv[8];
#pragma unroll
        for (int r = 0; r < 8; ++r) gv[r] = ld_uc4_nw(gb + xOff[r]);
        asm volatile("s_waitcnt vmcnt(0)" ::: "memory");
        __builtin_amdgcn_sched_barrier(0);

#pragma unroll
        for (int r = 0; r < 8; ++r)
#pragma unroll
            for (int c = 0; c < 8; ++c)
                v[r * 8 + c] = gv[r].x * cv[c].x + gv[r].y * cv[c].y
                             + gv[r].z * cv[c].z + gv[r].w * cv[c].w;
#pragma unroll
        for (int j = 0; j < 32; ++j) v[j] = v[2 * j] + __shfl_xor(v[2 * j + 1], 1);
#pragma unroll
        for (int j = 0; j < 16; ++j) v[j] = v[2 * j] + __shfl_xor(v[2 * j + 1], 2);
#pragma unroll
        for (int j = 0; j < 8; ++j)  v[j] = v[2 * j] + __shfl_xor(v[2 * j + 1], 4);
#pragma unroll
        for (int j = 0; j < 4; ++j)  v[j] = v[2 * j] + __shfl_xor(v[2 * j + 1], 8);
#pragma unroll
        for (int j = 0; j < 2; ++j)  v[j] = v[2 * j] + __shfl_xor(v[2 * j + 1], 16);
        v[0] = v[0] + __shfl_xor(v[1], 32);
        scrB[w * 64 + L] = v[0];
        __syncthreads();                  // sync2

        if (w == 4) {                     // epilogue B: gates + cell, publish tagH
            float pf0 = scrB[(0 + e_cg) * 64 + e_s0], pi0 = scrB[(2 + e_cg) * 64 + e_s0];
            float pg0 = scrB[(4 + e_cg) * 64 + e_s0], po0 = scrB[(6 + e_cg) * 64 + e_s0];
            float pf1 = scrB[(0 + e_cg) * 64 + e_s1], pi1 = scrB[(2 + e_cg) * 64 + e_s1];
            float pg1 = scrB[(4 + e_cg) * 64 + e_s1], po1 = scrB[(6 + e_cg) * 64 + e_s1];
            float ft = 1.f / (1.f + __expf(-pf0));
            float it = 1.f / (1.f + __expf(-pi0));
            float gt = tanhf(pg0);
            float ot = 1.f / (1.f + __expf(-po0));
            creg0 = ft * creg0 + it * gt;
            float hv0 = ot * tanhf(creg0);
            ft = 1.f / (1.f + __expf(-pf1));
            it = 1.f / (1.f + __expf(-pi1));
            gt = tanhf(pg1);
            ot = 1.f / (1.f + __expf(-po1));
            creg1 = ft * creg1 + it * gt;
            float hv1 = ot * tanhf(creg1);
            float* hw = h_buf + (t & 1) * 32768;
            st_uc(hw + (size_t)bglob0 * 1024 + e_col, hv0);
            st_uc(hw + (size_t)bglob1 * 1024 + e_col, hv1);
            st_uc(XBH + ((size_t)bglob0 * 512 + t) * 1024 + e_col, hv0);
            st_uc(XBH + ((size_t)bglob1 * 512 + t) * 1024 + e_col, hv1);
            if (t == 511) {
                st_uc(ht_out + (size_t)bglob0 * 1024 + e_col, hv0);
                st_uc(ht_out + (size_t)bglob1 * 1024 + e_col, hv1);
                st_uc(ct_out + (size_t)bglob0 * 1024 + e_col, creg0);
                st_uc(ct_out + (size_t)bglob1 * 1024 + e_col, creg1);
            }
            asm volatile("s_waitcnt vmcnt(0)" ::: "memory");
            if (L == 0) st_uc_u(tagH + sg, tu + 1u);
        }
    }
}

// ---------------------------------------------------------------- launch
extern "C" void kernel_launch(void* const* d_in, const int* in_sizes, int n_in,
                              void* d_out, int out_size, void* d_ws, size_t ws_size,
                              hipStream_t stream) {
    const float* X   = (const float*)d_in[0];
    const float* A   = (const float*)d_in[1];
    const float* Bw  = (const float*)d_in[2];
    const float* CTm = (const float*)d_in[3];

    float* out    = (float*)d_out;
    float* XBH    = out;                                  // xb in, hidden_seq out
    float* ht_out = out + (size_t)32 * 512 * 1024;
    float* ct_out = ht_out + 32 * 1024;

    float* h_buf = (float*)d_ws;                          // 2 x 32768 floats
    float* g_buf = h_buf + 65536;                         // 2 x 32768 floats
    unsigned* tags = (unsigned*)(g_buf + 65536);          // 4 x 128 uints

    (void)hipFuncSetAttribute((const void*)scan_kernel,
                              hipFuncAttributeMaxDynamicSharedMemorySize, 135168);

    init_kernel<<<dim3(256), dim3(256), 0, stream>>>(h_buf, tags);
    xb_gemm<<<dim3(1024), dim3(256), 0, stream>>>(X, Bw, XBH);
    scan_kernel<<<dim3(256), dim3(NTHR), 135168, stream>>>(A, CTm, XBH, h_buf, g_buf,
                                                           ht_out, ct_out, tags);
}